// Round 11
// baseline (367.711 us; speedup 1.0000x reference)
//
#include <hip/hip_runtime.h>

#define D_MODEL 1024
#define NHEADS  16
#define DEPTH   64
#define BATCH   2
#define SEQ     2048
#define MROWS   (BATCH * SEQ)   // 4096
#define QSCALE  0.125f          // folded into Q projection; flash uses __expf directly

typedef unsigned short u16;
typedef unsigned int   u32;
typedef unsigned long long u64;
typedef __bf16 bf16x8 __attribute__((ext_vector_type(8)));
typedef float  f32x4  __attribute__((ext_vector_type(4)));

__device__ __forceinline__ u16 f2b(float f) {
    return __builtin_bit_cast(u16, static_cast<__bf16>(f));   // v_cvt RNE
}
__device__ __forceinline__ bf16x8 ldb8(const u16* p) {
    return __builtin_bit_cast(bf16x8, *(const uint4*)p);
}

// ---------------------------------------------------------------------------
// Merged Q/K/V projection + mask packing.
// z in {0,1,2}: dst = X·W^T + bias (BM=128 BN=128 BK=32, register-prefetch
//   double-buffer; z==0 output pre-scaled by QSCALE; z==2 transposed store).
// z == 3: pack mask f32 [B,S,S] into bit-words (word (b*S+q)*32+k64), one
//   wave per 64-float ballot, 512 words per block. Grid (8,32,4).
// ---------------------------------------------------------------------------
__global__ __launch_bounds__(256, 3) void proj3(
    const float* __restrict__ q, const float* __restrict__ k, const float* __restrict__ v,
    const float* __restrict__ wq, const float* __restrict__ wk, const float* __restrict__ wv,
    const float* __restrict__ bq, const float* __restrict__ bk, const float* __restrict__ bv,
    u16* __restrict__ qws, u16* __restrict__ kws, u16* __restrict__ vtws,
    const float* __restrict__ mask, u64* __restrict__ bits)
{
    __shared__ __align__(16) u16 ldsA[128 * 40];
    __shared__ __align__(16) u16 ldsB[128 * 40];

    const int z = blockIdx.z;

    if (z == 3) {
        // mask packing slice: 256 blocks × 4 waves × 128 words
        const int blk  = blockIdx.y * 8 + blockIdx.x;        // 0..255
        const int wvm  = threadIdx.x >> 6;
        const int lane = threadIdx.x & 63;
        size_t w0 = (size_t)blk * 512 + (size_t)wvm * 128;
        for (int i = 0; i < 128; ++i) {
            size_t w = w0 + i;
            float m = mask[w * 64 + lane];
            u64 bb = __ballot(m > 0.5f);
            if (lane == 0) bits[w] = bb;
        }
        return;
    }

    const float* X  = (z == 0) ? q  : (z == 1) ? k  : v;
    const float* W  = (z == 0) ? wq : (z == 1) ? wk : wv;
    const float* Bi = (z == 0) ? bq : (z == 1) ? bk : bv;
    u16* dst        = (z == 0) ? qws : (z == 1) ? kws : vtws;

    const int tid  = threadIdx.x;
    const int wv_  = tid >> 6;
    const int lane = tid & 63;
    const int quad = lane >> 4;
    const int l15  = lane & 15;
    const int bx = blockIdx.x, by = blockIdx.y;
    const int wm = (wv_ >> 1) * 64;
    const int wn = (wv_ & 1) * 64;

    f32x4 acc[4][4];
    for (int i = 0; i < 4; ++i)
        for (int j = 0; j < 4; ++j)
            acc[i][j] = (f32x4){0.f, 0.f, 0.f, 0.f};

    const int rowA0 = by * 128;
    const int rowB0 = bx * 128;

    const int sr = tid >> 3;
    const int sc = (tid & 7) * 4;

    float4 pa[4], pb[4];
    #pragma unroll
    for (int i = 0; i < 4; ++i) {
        pa[i] = *(const float4*)&X[(size_t)(rowA0 + sr + i * 32) * D_MODEL + sc];
        pb[i] = *(const float4*)&W[(size_t)(rowB0 + sr + i * 32) * D_MODEL + sc];
    }

    for (int it = 0; it < 32; ++it) {
        #pragma unroll
        for (int i = 0; i < 4; ++i) {
            ushort4 ha, hb;
            ha.x = f2b(pa[i].x); ha.y = f2b(pa[i].y); ha.z = f2b(pa[i].z); ha.w = f2b(pa[i].w);
            hb.x = f2b(pb[i].x); hb.y = f2b(pb[i].y); hb.z = f2b(pb[i].z); hb.w = f2b(pb[i].w);
            *(ushort4*)&ldsA[(sr + i * 32) * 40 + sc] = ha;
            *(ushort4*)&ldsB[(sr + i * 32) * 40 + sc] = hb;
        }
        __syncthreads();

        if (it < 31) {
            const int k0 = (it + 1) * 32;
            #pragma unroll
            for (int i = 0; i < 4; ++i) {
                pa[i] = *(const float4*)&X[(size_t)(rowA0 + sr + i * 32) * D_MODEL + k0 + sc];
                pb[i] = *(const float4*)&W[(size_t)(rowB0 + sr + i * 32) * D_MODEL + k0 + sc];
            }
        }

        bf16x8 af[4], bfr[4];
        #pragma unroll
        for (int t = 0; t < 4; ++t) {
            af[t]  = ldb8(&ldsA[(wm + t * 16 + l15) * 40 + quad * 8]);
            bfr[t] = ldb8(&ldsB[(wn + t * 16 + l15) * 40 + quad * 8]);
        }
        #pragma unroll
        for (int mt = 0; mt < 4; ++mt)
            #pragma unroll
            for (int nt = 0; nt < 4; ++nt)
                acc[mt][nt] = __builtin_amdgcn_mfma_f32_16x16x32_bf16(af[mt], bfr[nt], acc[mt][nt], 0, 0, 0);
        __syncthreads();
    }

    #pragma unroll
    for (int nt = 0; nt < 4; ++nt) {
        int n = bx * 128 + wn + nt * 16 + l15;
        float bvv = Bi[n];
        int h = n >> 6, d = n & 63;
        #pragma unroll
        for (int mt = 0; mt < 4; ++mt) {
            #pragma unroll
            for (int r = 0; r < 4; ++r) {
                int m = by * 128 + wm + mt * 16 + quad * 4 + r;
                float c = acc[mt][nt][r] + bvv;
                if (z == 0) c *= QSCALE;
                int b = m >> 11, s = m & (SEQ - 1);
                if (z != 2)
                    dst[(((size_t)(b * NHEADS + h) * SEQ) + s) * DEPTH + d] = f2b(c);
                else
                    dst[(((size_t)(b * NHEADS + h) * DEPTH) + d) * SEQ + s] = f2b(c);
            }
        }
    }
}

// ---------------------------------------------------------------------------
// Output projection: O bf16 · Wo^T(f32, fused cvt) + bo. BM=128 BN=64 dbuf.
// Grid (16,32) = 512 blocks.
// ---------------------------------------------------------------------------
__global__ __launch_bounds__(256) void gemm_out(
    const u16* __restrict__ X, const float* __restrict__ W,
    const float* __restrict__ bias, float* __restrict__ out)
{
    __shared__ __align__(16) u16 ldsA[128 * 40];
    __shared__ __align__(16) u16 ldsB[64 * 40];

    const int tid  = threadIdx.x;
    const int wv_  = tid >> 6;
    const int lane = tid & 63;
    const int quad = lane >> 4;
    const int l15  = lane & 15;
    const int bx = blockIdx.x, by = blockIdx.y;
    const int wm = (wv_ >> 1) * 64;
    const int wn = (wv_ & 1) * 32;

    f32x4 acc[4][2];
    for (int i = 0; i < 4; ++i)
        for (int j = 0; j < 2; ++j)
            acc[i][j] = (f32x4){0.f, 0.f, 0.f, 0.f};

    const int rowA0 = by * 128;
    const int rowB0 = bx * 64;

    const int ar = tid >> 2, akc = (tid & 3) * 8;
    const int br = tid >> 3, bc = (tid & 7) * 4;

    uint4  paA[2];
    float4 paB[2];
    #pragma unroll
    for (int i = 0; i < 2; ++i) {
        paA[i] = *(const uint4*)&X[(size_t)(rowA0 + ar + i * 64) * D_MODEL + akc];
        paB[i] = *(const float4*)&W[(size_t)(rowB0 + br + i * 32) * D_MODEL + bc];
    }

    for (int it = 0; it < 32; ++it) {
        #pragma unroll
        for (int i = 0; i < 2; ++i) {
            *(uint4*)&ldsA[(ar + i * 64) * 40 + akc] = paA[i];
            ushort4 hb;
            hb.x = f2b(paB[i].x); hb.y = f2b(paB[i].y); hb.z = f2b(paB[i].z); hb.w = f2b(paB[i].w);
            *(ushort4*)&ldsB[(br + i * 32) * 40 + bc] = hb;
        }
        __syncthreads();

        if (it < 31) {
            const int k0 = (it + 1) * 32;
            #pragma unroll
            for (int i = 0; i < 2; ++i) {
                paA[i] = *(const uint4*)&X[(size_t)(rowA0 + ar + i * 64) * D_MODEL + k0 + akc];
                paB[i] = *(const float4*)&W[(size_t)(rowB0 + br + i * 32) * D_MODEL + k0 + bc];
            }
        }

        bf16x8 af[4], bfr[2];
        #pragma unroll
        for (int t = 0; t < 4; ++t)
            af[t] = ldb8(&ldsA[(wm + t * 16 + l15) * 40 + quad * 8]);
        #pragma unroll
        for (int t = 0; t < 2; ++t)
            bfr[t] = ldb8(&ldsB[(wn + t * 16 + l15) * 40 + quad * 8]);
        #pragma unroll
        for (int mt = 0; mt < 4; ++mt)
            #pragma unroll
            for (int nt = 0; nt < 2; ++nt)
                acc[mt][nt] = __builtin_amdgcn_mfma_f32_16x16x32_bf16(af[mt], bfr[nt], acc[mt][nt], 0, 0, 0);
        __syncthreads();
    }

    #pragma unroll
    for (int nt = 0; nt < 2; ++nt) {
        int n = bx * 64 + wn + nt * 16 + l15;
        float bvv = bias[n];
        #pragma unroll
        for (int mt = 0; mt < 4; ++mt) {
            #pragma unroll
            for (int r = 0; r < 4; ++r) {
                int m = by * 128 + wm + mt * 16 + quad * 4 + r;
                out[(size_t)m * D_MODEL + n] = acc[mt][nt][r] + bvv;
            }
        }
    }
}

// ---------------------------------------------------------------------------
// Flash attention: LDS-staged dbuf K/V, packed mask bits (1 shift/row),
// Q pre-scaled by 0.125 so p = __expf(score) directly (fast OCML path).
// Grid (S/64, B*H). Q,K: [B,H,S,64] bf16; Vt: [B,H,64,S] bf16.
// ---------------------------------------------------------------------------
__global__ __launch_bounds__(256, 3) void flash_attn(
    const u16* __restrict__ Q, const u16* __restrict__ K,
    const u16* __restrict__ Vt, const u64* __restrict__ maskbits,
    u16* __restrict__ O)
{
    __shared__ __align__(16) u16 ldsK[2][64 * 64];
    __shared__ __align__(16) u16 ldsV[2][64 * 64];
    __shared__ __align__(16) u16 ldsP[4][16 * 72];

    const int tid  = threadIdx.x;
    const int wv_  = tid >> 6;
    const int lane = tid & 63;
    const int quad = lane >> 4;
    const int l15  = lane & 15;
    const int bh = blockIdx.y;
    const int b  = bh >> 4, h = bh & 15;
    const int q0 = blockIdx.x * 64 + wv_ * 16;

    const u16* Qb = Q  + (size_t)bh * SEQ * DEPTH;
    const u16* Kb = K  + (size_t)bh * SEQ * DEPTH;
    const u16* Vb = Vt + (size_t)bh * DEPTH * SEQ;
    const u64* MB = maskbits + (size_t)b * SEQ * (SEQ / 64);

    const int srow = tid >> 3;
    const int sc8  = tid & 7;
    const int swz  = ((sc8 ^ (srow & 7)) * 8);
    const int kdst0 = srow * 64 + swz;
    const int kdst1 = (srow + 32) * 64 + swz;

    const int xk0 = ((quad ^ (l15 & 7)) * 8);
    const int xk1 = (((4 + quad) ^ (l15 & 7)) * 8);

    bf16x8 aq0 = ldb8(&Qb[(q0 + l15) * DEPTH + quad * 8]);
    bf16x8 aq1 = ldb8(&Qb[(q0 + l15) * DEPTH + 32 + quad * 8]);

    f32x4 oa[4];
    for (int i = 0; i < 4; ++i) oa[i] = (f32x4){0.f, 0.f, 0.f, 0.f};
    float lrow[4] = {0.f, 0.f, 0.f, 0.f};

    u16* myP = ldsP[wv_];

    uint4 kreg0 = *(const uint4*)&Kb[(size_t)srow * DEPTH + sc8 * 8];
    uint4 kreg1 = *(const uint4*)&Kb[(size_t)(srow + 32) * DEPTH + sc8 * 8];
    uint4 vreg0 = *(const uint4*)&Vb[(size_t)srow * SEQ + sc8 * 8];
    uint4 vreg1 = *(const uint4*)&Vb[(size_t)(srow + 32) * SEQ + sc8 * 8];

    for (int it = 0; it < 32; ++it) {
        const int buf = it & 1;
        u16* Kl = ldsK[buf];
        u16* Vl = ldsV[buf];

        *(uint4*)&Kl[kdst0] = kreg0;
        *(uint4*)&Kl[kdst1] = kreg1;
        *(uint4*)&Vl[kdst0] = vreg0;
        *(uint4*)&Vl[kdst1] = vreg1;
        __syncthreads();

        if (it < 31) {
            const int kb2 = (it + 1) * 64;
            kreg0 = *(const uint4*)&Kb[(size_t)(kb2 + srow) * DEPTH + sc8 * 8];
            kreg1 = *(const uint4*)&Kb[(size_t)(kb2 + srow + 32) * DEPTH + sc8 * 8];
            vreg0 = *(const uint4*)&Vb[(size_t)srow * SEQ + kb2 + sc8 * 8];
            vreg1 = *(const uint4*)&Vb[(size_t)(srow + 32) * SEQ + kb2 + sc8 * 8];
        }

        u32 tlo[4], thi[4];
        #pragma unroll
        for (int r = 0; r < 4; ++r) {
            u64 t = MB[(size_t)(q0 + quad * 4 + r) * (SEQ / 64) + it] >> l15;
            tlo[r] = (u32)t;
            thi[r] = (u32)(t >> 32);
        }

        #pragma unroll
        for (int cc = 0; cc < 4; ++cc) {
            const int row = cc * 16 + l15;
            bf16x8 bk0 = ldb8(&Kl[row * 64 + xk0]);
            bf16x8 bk1 = ldb8(&Kl[row * 64 + xk1]);
            f32x4 z = (f32x4){0.f, 0.f, 0.f, 0.f};
            z = __builtin_amdgcn_mfma_f32_16x16x32_bf16(aq0, bk0, z, 0, 0, 0);
            z = __builtin_amdgcn_mfma_f32_16x16x32_bf16(aq1, bk1, z, 0, 0, 0);
            #pragma unroll
            for (int r = 0; r < 4; ++r) {
                u32 w   = (cc < 2) ? tlo[r] : thi[r];
                u32 bit = (cc & 1) ? ((w >> 16) & 1u) : (w & 1u);
                float e = __expf(z[r]);          // Q pre-scaled by 0.125
                float p = bit ? 0.f : e;
                lrow[r] += p;
                myP[(quad * 4 + r) * 72 + cc * 16 + l15] = f2b(p);
            }
        }

        __builtin_amdgcn_wave_barrier();
        __builtin_amdgcn_s_waitcnt(0xc07f);   // lgkmcnt(0)
        __builtin_amdgcn_wave_barrier();
        bf16x8 pa0 = ldb8(&myP[l15 * 72 + quad * 8]);
        bf16x8 pa1 = ldb8(&myP[l15 * 72 + 32 + quad * 8]);

        #pragma unroll
        for (int n = 0; n < 4; ++n) {
            const int row = n * 16 + l15;
            bf16x8 bv0 = ldb8(&Vl[row * 64 + xk0]);
            bf16x8 bv1 = ldb8(&Vl[row * 64 + xk1]);
            oa[n] = __builtin_amdgcn_mfma_f32_16x16x32_bf16(pa0, bv0, oa[n], 0, 0, 0);
            oa[n] = __builtin_amdgcn_mfma_f32_16x16x32_bf16(pa1, bv1, oa[n], 0, 0, 0);
        }
    }

    #pragma unroll
    for (int r = 0; r < 4; ++r) {
        float s = lrow[r];
        #pragma unroll
        for (int off = 1; off < 16; off <<= 1)
            s += __shfl_xor(s, off, 64);
        lrow[r] = 1.0f / s;
    }
    #pragma unroll
    for (int n = 0; n < 4; ++n)
        #pragma unroll
        for (int r = 0; r < 4; ++r) {
            int m = q0 + quad * 4 + r;
            O[((size_t)b * SEQ + m) * D_MODEL + h * DEPTH + n * 16 + l15] =
                f2b(oa[n][r] * lrow[r]);
        }
}

// ---------------------------------------------------------------------------
extern "C" void kernel_launch(void* const* d_in, const int* in_sizes, int n_in,
                              void* d_out, int out_size, void* d_ws, size_t ws_size,
                              hipStream_t stream) {
    const float* q    = (const float*)d_in[0];
    const float* k    = (const float*)d_in[1];
    const float* v    = (const float*)d_in[2];
    const float* mask = (const float*)d_in[3];
    const float* wq   = (const float*)d_in[4];
    const float* bq   = (const float*)d_in[5];
    const float* wk   = (const float*)d_in[6];
    const float* bk   = (const float*)d_in[7];
    const float* wv   = (const float*)d_in[8];
    const float* bv   = (const float*)d_in[9];
    const float* wo   = (const float*)d_in[10];
    const float* bo   = (const float*)d_in[11];

    // ws: [qws 8MB][kws 8MB][vtws 8MB][ows 8MB][maskbits 1MB]
    u16* base = (u16*)d_ws;
    const size_t seg = (size_t)BATCH * NHEADS * SEQ * DEPTH;  // 4M elems
    u16* qws  = base;
    u16* kws  = base + seg;
    u16* vtws = base + 2 * seg;
    u16* ows  = base + 3 * seg;
    u64* mbits = (u64*)(base + 4 * seg);

    dim3 blk(256);
    dim3 gp(D_MODEL / 128, MROWS / 128, 4);   // (8, 32, 4): z=0..2 GEMM, z=3 mask pack
    hipLaunchKernelGGL(proj3, gp, blk, 0, stream,
                       q, k, v, wq, wk, wv, bq, bk, bv, qws, kws, vtws, mask, mbits);

    dim3 ga(SEQ / 64, BATCH * NHEADS);        // (32, 32)
    hipLaunchKernelGGL(flash_attn, ga, blk, 0, stream, qws, kws, vtws, mbits, ows);

    dim3 go(D_MODEL / 64, MROWS / 128);       // (16, 32)
    hipLaunchKernelGGL(gemm_out, go, blk, 0, stream, ows, wo, bo, (float*)d_out);
}

// Round 12
// 330.533 us; speedup vs baseline: 1.1125x; 1.1125x over previous
//
#include <hip/hip_runtime.h>

#define D_MODEL 1024
#define NHEADS  16
#define DEPTH   64
#define BATCH   2
#define SEQ     2048
#define MROWS   (BATCH * SEQ)   // 4096
#define QSCALE  0.125f          // folded into Q projection; flash uses __expf directly

typedef unsigned short u16;
typedef unsigned int   u32;
typedef unsigned long long u64;
typedef __bf16 bf16x8 __attribute__((ext_vector_type(8)));
typedef float  f32x4  __attribute__((ext_vector_type(4)));

__device__ __forceinline__ u16 f2b(float f) {
    return __builtin_bit_cast(u16, static_cast<__bf16>(f));   // v_cvt RNE
}
__device__ __forceinline__ bf16x8 ldb8(const u16* p) {
    return __builtin_bit_cast(bf16x8, *(const uint4*)p);
}

// ---------------------------------------------------------------------------
// Pack mask f32 [B,S,S] (1 => masked) into bit-words: word (b*S+q)*32 + k64.
// 2048 blocks × 4 waves × 1 word — fully parallel, ~8 µs.
// ---------------------------------------------------------------------------
__global__ __launch_bounds__(256) void pack_mask(
    const float* __restrict__ mask, u64* __restrict__ bits)
{
    const int w    = blockIdx.x * 4 + (threadIdx.x >> 6);
    const int lane = threadIdx.x & 63;
    float m = mask[(size_t)w * 64 + lane];
    u64 b = __ballot(m > 0.5f);
    if (lane == 0) bits[w] = b;
}

// ---------------------------------------------------------------------------
// Merged Q/K/V projection: f32 operands, f32->bf16 fused into staging.
// BM=128 BN=128 BK=32, register-prefetch double-buffer.
// z==0 (Q) output pre-scaled by QSCALE; z==2 (V) transposed store.
// Grid (8,32,3) = 768 blocks.
// ---------------------------------------------------------------------------
__global__ __launch_bounds__(256, 3) void proj3(
    const float* __restrict__ q, const float* __restrict__ k, const float* __restrict__ v,
    const float* __restrict__ wq, const float* __restrict__ wk, const float* __restrict__ wv,
    const float* __restrict__ bq, const float* __restrict__ bk, const float* __restrict__ bv,
    u16* __restrict__ qws, u16* __restrict__ kws, u16* __restrict__ vtws)
{
    __shared__ __align__(16) u16 ldsA[128 * 40];
    __shared__ __align__(16) u16 ldsB[128 * 40];

    const int z = blockIdx.z;
    const float* X  = (z == 0) ? q  : (z == 1) ? k  : v;
    const float* W  = (z == 0) ? wq : (z == 1) ? wk : wv;
    const float* Bi = (z == 0) ? bq : (z == 1) ? bk : bv;
    u16* dst        = (z == 0) ? qws : (z == 1) ? kws : vtws;

    const int tid  = threadIdx.x;
    const int wv_  = tid >> 6;
    const int lane = tid & 63;
    const int quad = lane >> 4;
    const int l15  = lane & 15;
    const int bx = blockIdx.x, by = blockIdx.y;
    const int wm = (wv_ >> 1) * 64;
    const int wn = (wv_ & 1) * 64;

    f32x4 acc[4][4];
    for (int i = 0; i < 4; ++i)
        for (int j = 0; j < 4; ++j)
            acc[i][j] = (f32x4){0.f, 0.f, 0.f, 0.f};

    const int rowA0 = by * 128;
    const int rowB0 = bx * 128;

    const int sr = tid >> 3;
    const int sc = (tid & 7) * 4;

    float4 pa[4], pb[4];
    #pragma unroll
    for (int i = 0; i < 4; ++i) {
        pa[i] = *(const float4*)&X[(size_t)(rowA0 + sr + i * 32) * D_MODEL + sc];
        pb[i] = *(const float4*)&W[(size_t)(rowB0 + sr + i * 32) * D_MODEL + sc];
    }

    for (int it = 0; it < 32; ++it) {
        #pragma unroll
        for (int i = 0; i < 4; ++i) {
            ushort4 ha, hb;
            ha.x = f2b(pa[i].x); ha.y = f2b(pa[i].y); ha.z = f2b(pa[i].z); ha.w = f2b(pa[i].w);
            hb.x = f2b(pb[i].x); hb.y = f2b(pb[i].y); hb.z = f2b(pb[i].z); hb.w = f2b(pb[i].w);
            *(ushort4*)&ldsA[(sr + i * 32) * 40 + sc] = ha;
            *(ushort4*)&ldsB[(sr + i * 32) * 40 + sc] = hb;
        }
        __syncthreads();

        if (it < 31) {
            const int k0 = (it + 1) * 32;
            #pragma unroll
            for (int i = 0; i < 4; ++i) {
                pa[i] = *(const float4*)&X[(size_t)(rowA0 + sr + i * 32) * D_MODEL + k0 + sc];
                pb[i] = *(const float4*)&W[(size_t)(rowB0 + sr + i * 32) * D_MODEL + k0 + sc];
            }
        }

        bf16x8 af[4], bfr[4];
        #pragma unroll
        for (int t = 0; t < 4; ++t) {
            af[t]  = ldb8(&ldsA[(wm + t * 16 + l15) * 40 + quad * 8]);
            bfr[t] = ldb8(&ldsB[(wn + t * 16 + l15) * 40 + quad * 8]);
        }
        #pragma unroll
        for (int mt = 0; mt < 4; ++mt)
            #pragma unroll
            for (int nt = 0; nt < 4; ++nt)
                acc[mt][nt] = __builtin_amdgcn_mfma_f32_16x16x32_bf16(af[mt], bfr[nt], acc[mt][nt], 0, 0, 0);
        __syncthreads();
    }

    #pragma unroll
    for (int nt = 0; nt < 4; ++nt) {
        int n = bx * 128 + wn + nt * 16 + l15;
        float bvv = Bi[n];
        int h = n >> 6, d = n & 63;
        #pragma unroll
        for (int mt = 0; mt < 4; ++mt) {
            #pragma unroll
            for (int r = 0; r < 4; ++r) {
                int m = by * 128 + wm + mt * 16 + quad * 4 + r;
                float c = acc[mt][nt][r] + bvv;
                if (z == 0) c *= QSCALE;
                int b = m >> 11, s = m & (SEQ - 1);
                if (z != 2)
                    dst[(((size_t)(b * NHEADS + h) * SEQ) + s) * DEPTH + d] = f2b(c);
                else
                    dst[(((size_t)(b * NHEADS + h) * DEPTH) + d) * SEQ + s] = f2b(c);
            }
        }
    }
}

// ---------------------------------------------------------------------------
// Output projection: O bf16 · Wo^T(f32, fused cvt) + bo. BM=128 BN=64 dbuf.
// Grid (16,32) = 512 blocks.
// ---------------------------------------------------------------------------
__global__ __launch_bounds__(256) void gemm_out(
    const u16* __restrict__ X, const float* __restrict__ W,
    const float* __restrict__ bias, float* __restrict__ out)
{
    __shared__ __align__(16) u16 ldsA[128 * 40];
    __shared__ __align__(16) u16 ldsB[64 * 40];

    const int tid  = threadIdx.x;
    const int wv_  = tid >> 6;
    const int lane = tid & 63;
    const int quad = lane >> 4;
    const int l15  = lane & 15;
    const int bx = blockIdx.x, by = blockIdx.y;
    const int wm = (wv_ >> 1) * 64;
    const int wn = (wv_ & 1) * 32;

    f32x4 acc[4][2];
    for (int i = 0; i < 4; ++i)
        for (int j = 0; j < 2; ++j)
            acc[i][j] = (f32x4){0.f, 0.f, 0.f, 0.f};

    const int rowA0 = by * 128;
    const int rowB0 = bx * 64;

    const int ar = tid >> 2, akc = (tid & 3) * 8;
    const int br = tid >> 3, bc = (tid & 7) * 4;

    uint4  paA[2];
    float4 paB[2];
    #pragma unroll
    for (int i = 0; i < 2; ++i) {
        paA[i] = *(const uint4*)&X[(size_t)(rowA0 + ar + i * 64) * D_MODEL + akc];
        paB[i] = *(const float4*)&W[(size_t)(rowB0 + br + i * 32) * D_MODEL + bc];
    }

    for (int it = 0; it < 32; ++it) {
        #pragma unroll
        for (int i = 0; i < 2; ++i) {
            *(uint4*)&ldsA[(ar + i * 64) * 40 + akc] = paA[i];
            ushort4 hb;
            hb.x = f2b(paB[i].x); hb.y = f2b(paB[i].y); hb.z = f2b(paB[i].z); hb.w = f2b(paB[i].w);
            *(ushort4*)&ldsB[(br + i * 32) * 40 + bc] = hb;
        }
        __syncthreads();

        if (it < 31) {
            const int k0 = (it + 1) * 32;
            #pragma unroll
            for (int i = 0; i < 2; ++i) {
                paA[i] = *(const uint4*)&X[(size_t)(rowA0 + ar + i * 64) * D_MODEL + k0 + akc];
                paB[i] = *(const float4*)&W[(size_t)(rowB0 + br + i * 32) * D_MODEL + k0 + bc];
            }
        }

        bf16x8 af[4], bfr[2];
        #pragma unroll
        for (int t = 0; t < 4; ++t)
            af[t] = ldb8(&ldsA[(wm + t * 16 + l15) * 40 + quad * 8]);
        #pragma unroll
        for (int t = 0; t < 2; ++t)
            bfr[t] = ldb8(&ldsB[(wn + t * 16 + l15) * 40 + quad * 8]);
        #pragma unroll
        for (int mt = 0; mt < 4; ++mt)
            #pragma unroll
            for (int nt = 0; nt < 2; ++nt)
                acc[mt][nt] = __builtin_amdgcn_mfma_f32_16x16x32_bf16(af[mt], bfr[nt], acc[mt][nt], 0, 0, 0);
        __syncthreads();
    }

    #pragma unroll
    for (int nt = 0; nt < 2; ++nt) {
        int n = bx * 64 + wn + nt * 16 + l15;
        float bvv = bias[n];
        #pragma unroll
        for (int mt = 0; mt < 4; ++mt) {
            #pragma unroll
            for (int r = 0; r < 4; ++r) {
                int m = by * 128 + wm + mt * 16 + quad * 4 + r;
                out[(size_t)m * D_MODEL + n] = acc[mt][nt][r] + bvv;
            }
        }
    }
}

// ---------------------------------------------------------------------------
// Flash attention: LDS-staged dbuf K/V, packed mask bits (1 shift/row),
// Q pre-scaled by 0.125 so p = __expf(score) directly (fast OCML path).
// Grid (S/64, B*H). Q,K: [B,H,S,64] bf16; Vt: [B,H,64,S] bf16.
// ---------------------------------------------------------------------------
__global__ __launch_bounds__(256, 3) void flash_attn(
    const u16* __restrict__ Q, const u16* __restrict__ K,
    const u16* __restrict__ Vt, const u64* __restrict__ maskbits,
    u16* __restrict__ O)
{
    __shared__ __align__(16) u16 ldsK[2][64 * 64];
    __shared__ __align__(16) u16 ldsV[2][64 * 64];
    __shared__ __align__(16) u16 ldsP[4][16 * 72];

    const int tid  = threadIdx.x;
    const int wv_  = tid >> 6;
    const int lane = tid & 63;
    const int quad = lane >> 4;
    const int l15  = lane & 15;
    const int bh = blockIdx.y;
    const int b  = bh >> 4, h = bh & 15;
    const int q0 = blockIdx.x * 64 + wv_ * 16;

    const u16* Qb = Q  + (size_t)bh * SEQ * DEPTH;
    const u16* Kb = K  + (size_t)bh * SEQ * DEPTH;
    const u16* Vb = Vt + (size_t)bh * DEPTH * SEQ;
    const u64* MB = maskbits + (size_t)b * SEQ * (SEQ / 64);

    const int srow = tid >> 3;
    const int sc8  = tid & 7;
    const int swz  = ((sc8 ^ (srow & 7)) * 8);
    const int kdst0 = srow * 64 + swz;
    const int kdst1 = (srow + 32) * 64 + swz;

    const int xk0 = ((quad ^ (l15 & 7)) * 8);
    const int xk1 = (((4 + quad) ^ (l15 & 7)) * 8);

    bf16x8 aq0 = ldb8(&Qb[(q0 + l15) * DEPTH + quad * 8]);
    bf16x8 aq1 = ldb8(&Qb[(q0 + l15) * DEPTH + 32 + quad * 8]);

    f32x4 oa[4];
    for (int i = 0; i < 4; ++i) oa[i] = (f32x4){0.f, 0.f, 0.f, 0.f};
    float lrow[4] = {0.f, 0.f, 0.f, 0.f};

    u16* myP = ldsP[wv_];

    uint4 kreg0 = *(const uint4*)&Kb[(size_t)srow * DEPTH + sc8 * 8];
    uint4 kreg1 = *(const uint4*)&Kb[(size_t)(srow + 32) * DEPTH + sc8 * 8];
    uint4 vreg0 = *(const uint4*)&Vb[(size_t)srow * SEQ + sc8 * 8];
    uint4 vreg1 = *(const uint4*)&Vb[(size_t)(srow + 32) * SEQ + sc8 * 8];

    for (int it = 0; it < 32; ++it) {
        const int buf = it & 1;
        u16* Kl = ldsK[buf];
        u16* Vl = ldsV[buf];

        *(uint4*)&Kl[kdst0] = kreg0;
        *(uint4*)&Kl[kdst1] = kreg1;
        *(uint4*)&Vl[kdst0] = vreg0;
        *(uint4*)&Vl[kdst1] = vreg1;
        __syncthreads();

        if (it < 31) {
            const int kb2 = (it + 1) * 64;
            kreg0 = *(const uint4*)&Kb[(size_t)(kb2 + srow) * DEPTH + sc8 * 8];
            kreg1 = *(const uint4*)&Kb[(size_t)(kb2 + srow + 32) * DEPTH + sc8 * 8];
            vreg0 = *(const uint4*)&Vb[(size_t)srow * SEQ + kb2 + sc8 * 8];
            vreg1 = *(const uint4*)&Vb[(size_t)(srow + 32) * SEQ + kb2 + sc8 * 8];
        }

        u32 tlo[4], thi[4];
        #pragma unroll
        for (int r = 0; r < 4; ++r) {
            u64 t = MB[(size_t)(q0 + quad * 4 + r) * (SEQ / 64) + it] >> l15;
            tlo[r] = (u32)t;
            thi[r] = (u32)(t >> 32);
        }

        #pragma unroll
        for (int cc = 0; cc < 4; ++cc) {
            const int row = cc * 16 + l15;
            bf16x8 bk0 = ldb8(&Kl[row * 64 + xk0]);
            bf16x8 bk1 = ldb8(&Kl[row * 64 + xk1]);
            f32x4 z = (f32x4){0.f, 0.f, 0.f, 0.f};
            z = __builtin_amdgcn_mfma_f32_16x16x32_bf16(aq0, bk0, z, 0, 0, 0);
            z = __builtin_amdgcn_mfma_f32_16x16x32_bf16(aq1, bk1, z, 0, 0, 0);
            #pragma unroll
            for (int r = 0; r < 4; ++r) {
                u32 w   = (cc < 2) ? tlo[r] : thi[r];
                u32 bit = (cc & 1) ? ((w >> 16) & 1u) : (w & 1u);
                float e = __expf(z[r]);          // Q pre-scaled by 0.125
                float p = bit ? 0.f : e;
                lrow[r] += p;
                myP[(quad * 4 + r) * 72 + cc * 16 + l15] = f2b(p);
            }
        }

        __builtin_amdgcn_wave_barrier();
        __builtin_amdgcn_s_waitcnt(0xc07f);   // lgkmcnt(0)
        __builtin_amdgcn_wave_barrier();
        bf16x8 pa0 = ldb8(&myP[l15 * 72 + quad * 8]);
        bf16x8 pa1 = ldb8(&myP[l15 * 72 + 32 + quad * 8]);

        #pragma unroll
        for (int n = 0; n < 4; ++n) {
            const int row = n * 16 + l15;
            bf16x8 bv0 = ldb8(&Vl[row * 64 + xk0]);
            bf16x8 bv1 = ldb8(&Vl[row * 64 + xk1]);
            oa[n] = __builtin_amdgcn_mfma_f32_16x16x32_bf16(pa0, bv0, oa[n], 0, 0, 0);
            oa[n] = __builtin_amdgcn_mfma_f32_16x16x32_bf16(pa1, bv1, oa[n], 0, 0, 0);
        }
    }

    #pragma unroll
    for (int r = 0; r < 4; ++r) {
        float s = lrow[r];
        #pragma unroll
        for (int off = 1; off < 16; off <<= 1)
            s += __shfl_xor(s, off, 64);
        lrow[r] = 1.0f / s;
    }
    #pragma unroll
    for (int n = 0; n < 4; ++n)
        #pragma unroll
        for (int r = 0; r < 4; ++r) {
            int m = q0 + quad * 4 + r;
            O[((size_t)b * SEQ + m) * D_MODEL + h * DEPTH + n * 16 + l15] =
                f2b(oa[n][r] * lrow[r]);
        }
}

// ---------------------------------------------------------------------------
extern "C" void kernel_launch(void* const* d_in, const int* in_sizes, int n_in,
                              void* d_out, int out_size, void* d_ws, size_t ws_size,
                              hipStream_t stream) {
    const float* q    = (const float*)d_in[0];
    const float* k    = (const float*)d_in[1];
    const float* v    = (const float*)d_in[2];
    const float* mask = (const float*)d_in[3];
    const float* wq   = (const float*)d_in[4];
    const float* bq   = (const float*)d_in[5];
    const float* wk   = (const float*)d_in[6];
    const float* bk   = (const float*)d_in[7];
    const float* wv   = (const float*)d_in[8];
    const float* bv   = (const float*)d_in[9];
    const float* wo   = (const float*)d_in[10];
    const float* bo   = (const float*)d_in[11];

    // ws: [qws 8MB][kws 8MB][vtws 8MB][ows 8MB][maskbits 1MB]
    u16* base = (u16*)d_ws;
    const size_t seg = (size_t)BATCH * NHEADS * SEQ * DEPTH;  // 4M elems
    u16* qws  = base;
    u16* kws  = base + seg;
    u16* vtws = base + 2 * seg;
    u16* ows  = base + 3 * seg;
    u64* mbits = (u64*)(base + 4 * seg);

    dim3 blk(256);
    hipLaunchKernelGGL(pack_mask, dim3(BATCH * SEQ * (SEQ / 64) / 4), blk, 0, stream, mask, mbits);

    dim3 gp(D_MODEL / 128, MROWS / 128, 3);   // (8, 32, 3)
    hipLaunchKernelGGL(proj3, gp, blk, 0, stream,
                       q, k, v, wq, wk, wv, bq, bk, bv, qws, kws, vtws);

    dim3 ga(SEQ / 64, BATCH * NHEADS);        // (32, 32)
    hipLaunchKernelGGL(flash_attn, ga, blk, 0, stream, qws, kws, vtws, mbits, ows);

    dim3 go(D_MODEL / 64, MROWS / 128);       // (16, 32)
    hipLaunchKernelGGL(gemm_out, go, blk, 0, stream, ows, wo, bo, (float*)d_out);
}

// Round 13
// 329.779 us; speedup vs baseline: 1.1150x; 1.0023x over previous
//
#include <hip/hip_runtime.h>

#define D_MODEL 1024
#define NHEADS  16
#define DEPTH   64
#define BATCH   2
#define SEQ     2048
#define MROWS   (BATCH * SEQ)   // 4096
#define QSCALE  0.125f          // folded into Q projection; flash uses __expf directly

typedef unsigned short u16;
typedef unsigned int   u32;
typedef unsigned long long u64;
typedef __bf16 bf16x8 __attribute__((ext_vector_type(8)));
typedef float  f32x4  __attribute__((ext_vector_type(4)));

__device__ __forceinline__ u16 f2b(float f) {
    return __builtin_bit_cast(u16, static_cast<__bf16>(f));   // v_cvt RNE
}
__device__ __forceinline__ bf16x8 ldb8(const u16* p) {
    return __builtin_bit_cast(bf16x8, *(const uint4*)p);
}

// ---------------------------------------------------------------------------
// Pack mask f32 [B,S,S] (1 => masked) into bit-words: word (b*S+q)*32 + k64.
// ---------------------------------------------------------------------------
__global__ __launch_bounds__(256) void pack_mask(
    const float* __restrict__ mask, u64* __restrict__ bits)
{
    const int w    = blockIdx.x * 4 + (threadIdx.x >> 6);
    const int lane = threadIdx.x & 63;
    float m = mask[(size_t)w * 64 + lane];
    u64 b = __ballot(m > 0.5f);
    if (lane == 0) bits[w] = b;
}

// ---------------------------------------------------------------------------
// Merged Q/K/V projection. Grid (8,32,3).
// XCD swizzle: blocks sharing an X-tile (same by) have identical blockIdx.x
// => identical (linear id % 8) => same XCD => X-tile L2-resident, fetched
// once per XCD instead of 8x.
// ---------------------------------------------------------------------------
__global__ __launch_bounds__(256, 3) void proj3(
    const float* __restrict__ q, const float* __restrict__ k, const float* __restrict__ v,
    const float* __restrict__ wq, const float* __restrict__ wk, const float* __restrict__ wv,
    const float* __restrict__ bq, const float* __restrict__ bk, const float* __restrict__ bv,
    u16* __restrict__ qws, u16* __restrict__ kws, u16* __restrict__ vtws)
{
    __shared__ __align__(16) u16 ldsA[128 * 40];
    __shared__ __align__(16) u16 ldsB[128 * 40];

    const int z = blockIdx.z;
    const float* X  = (z == 0) ? q  : (z == 1) ? k  : v;
    const float* W  = (z == 0) ? wq : (z == 1) ? wk : wv;
    const float* Bi = (z == 0) ? bq : (z == 1) ? bk : bv;
    u16* dst        = (z == 0) ? qws : (z == 1) ? kws : vtws;

    const int tid  = threadIdx.x;
    const int wv_  = tid >> 6;
    const int lane = tid & 63;
    const int quad = lane >> 4;
    const int l15  = lane & 15;
    // XCD-aware swizzle: by determined by blockIdx.x (the id%8 carrier)
    const int bx = blockIdx.y >> 2;                            // 0..7
    const int by = (blockIdx.x << 2) | (blockIdx.y & 3);       // 0..31
    const int wm = (wv_ >> 1) * 64;
    const int wn = (wv_ & 1) * 64;

    f32x4 acc[4][4];
    for (int i = 0; i < 4; ++i)
        for (int j = 0; j < 4; ++j)
            acc[i][j] = (f32x4){0.f, 0.f, 0.f, 0.f};

    const int rowA0 = by * 128;
    const int rowB0 = bx * 128;

    const int sr = tid >> 3;
    const int sc = (tid & 7) * 4;

    float4 pa[4], pb[4];
    #pragma unroll
    for (int i = 0; i < 4; ++i) {
        pa[i] = *(const float4*)&X[(size_t)(rowA0 + sr + i * 32) * D_MODEL + sc];
        pb[i] = *(const float4*)&W[(size_t)(rowB0 + sr + i * 32) * D_MODEL + sc];
    }

    for (int it = 0; it < 32; ++it) {
        #pragma unroll
        for (int i = 0; i < 4; ++i) {
            ushort4 ha, hb;
            ha.x = f2b(pa[i].x); ha.y = f2b(pa[i].y); ha.z = f2b(pa[i].z); ha.w = f2b(pa[i].w);
            hb.x = f2b(pb[i].x); hb.y = f2b(pb[i].y); hb.z = f2b(pb[i].z); hb.w = f2b(pb[i].w);
            *(ushort4*)&ldsA[(sr + i * 32) * 40 + sc] = ha;
            *(ushort4*)&ldsB[(sr + i * 32) * 40 + sc] = hb;
        }
        __syncthreads();

        if (it < 31) {
            const int k0 = (it + 1) * 32;
            #pragma unroll
            for (int i = 0; i < 4; ++i) {
                pa[i] = *(const float4*)&X[(size_t)(rowA0 + sr + i * 32) * D_MODEL + k0 + sc];
                pb[i] = *(const float4*)&W[(size_t)(rowB0 + sr + i * 32) * D_MODEL + k0 + sc];
            }
        }

        bf16x8 af[4], bfr[4];
        #pragma unroll
        for (int t = 0; t < 4; ++t) {
            af[t]  = ldb8(&ldsA[(wm + t * 16 + l15) * 40 + quad * 8]);
            bfr[t] = ldb8(&ldsB[(wn + t * 16 + l15) * 40 + quad * 8]);
        }
        #pragma unroll
        for (int mt = 0; mt < 4; ++mt)
            #pragma unroll
            for (int nt = 0; nt < 4; ++nt)
                acc[mt][nt] = __builtin_amdgcn_mfma_f32_16x16x32_bf16(af[mt], bfr[nt], acc[mt][nt], 0, 0, 0);
        __syncthreads();
    }

    #pragma unroll
    for (int nt = 0; nt < 4; ++nt) {
        int n = bx * 128 + wn + nt * 16 + l15;
        float bvv = Bi[n];
        int h = n >> 6, d = n & 63;
        #pragma unroll
        for (int mt = 0; mt < 4; ++mt) {
            #pragma unroll
            for (int r = 0; r < 4; ++r) {
                int m = by * 128 + wm + mt * 16 + quad * 4 + r;
                float c = acc[mt][nt][r] + bvv;
                if (z == 0) c *= QSCALE;
                int b = m >> 11, s = m & (SEQ - 1);
                if (z != 2)
                    dst[(((size_t)(b * NHEADS + h) * SEQ) + s) * DEPTH + d] = f2b(c);
                else
                    dst[(((size_t)(b * NHEADS + h) * DEPTH) + d) * SEQ + s] = f2b(c);
            }
        }
    }
}

// ---------------------------------------------------------------------------
// Output projection. Grid (16,32). XCD swizzle: blocks sharing an O-row-tile
// (same by) have identical (x & 7) => same XCD.
// ---------------------------------------------------------------------------
__global__ __launch_bounds__(256) void gemm_out(
    const u16* __restrict__ X, const float* __restrict__ W,
    const float* __restrict__ bias, float* __restrict__ out)
{
    __shared__ __align__(16) u16 ldsA[128 * 40];
    __shared__ __align__(16) u16 ldsB[64 * 40];

    const int tid  = threadIdx.x;
    const int wv_  = tid >> 6;
    const int lane = tid & 63;
    const int quad = lane >> 4;
    const int l15  = lane & 15;
    // XCD-aware swizzle
    const int bx = ((blockIdx.y >> 2) << 1) | (blockIdx.x >> 3);   // 0..15
    const int by = ((blockIdx.x & 7) << 2) | (blockIdx.y & 3);     // 0..31
    const int wm = (wv_ >> 1) * 64;
    const int wn = (wv_ & 1) * 32;

    f32x4 acc[4][2];
    for (int i = 0; i < 4; ++i)
        for (int j = 0; j < 2; ++j)
            acc[i][j] = (f32x4){0.f, 0.f, 0.f, 0.f};

    const int rowA0 = by * 128;
    const int rowB0 = bx * 64;

    const int ar = tid >> 2, akc = (tid & 3) * 8;
    const int br = tid >> 3, bc = (tid & 7) * 4;

    uint4  paA[2];
    float4 paB[2];
    #pragma unroll
    for (int i = 0; i < 2; ++i) {
        paA[i] = *(const uint4*)&X[(size_t)(rowA0 + ar + i * 64) * D_MODEL + akc];
        paB[i] = *(const float4*)&W[(size_t)(rowB0 + br + i * 32) * D_MODEL + bc];
    }

    for (int it = 0; it < 32; ++it) {
        #pragma unroll
        for (int i = 0; i < 2; ++i) {
            *(uint4*)&ldsA[(ar + i * 64) * 40 + akc] = paA[i];
            ushort4 hb;
            hb.x = f2b(paB[i].x); hb.y = f2b(paB[i].y); hb.z = f2b(paB[i].z); hb.w = f2b(paB[i].w);
            *(ushort4*)&ldsB[(br + i * 32) * 40 + bc] = hb;
        }
        __syncthreads();

        if (it < 31) {
            const int k0 = (it + 1) * 32;
            #pragma unroll
            for (int i = 0; i < 2; ++i) {
                paA[i] = *(const uint4*)&X[(size_t)(rowA0 + ar + i * 64) * D_MODEL + k0 + akc];
                paB[i] = *(const float4*)&W[(size_t)(rowB0 + br + i * 32) * D_MODEL + k0 + bc];
            }
        }

        bf16x8 af[4], bfr[2];
        #pragma unroll
        for (int t = 0; t < 4; ++t)
            af[t] = ldb8(&ldsA[(wm + t * 16 + l15) * 40 + quad * 8]);
        #pragma unroll
        for (int t = 0; t < 2; ++t)
            bfr[t] = ldb8(&ldsB[(wn + t * 16 + l15) * 40 + quad * 8]);
        #pragma unroll
        for (int mt = 0; mt < 4; ++mt)
            #pragma unroll
            for (int nt = 0; nt < 2; ++nt)
                acc[mt][nt] = __builtin_amdgcn_mfma_f32_16x16x32_bf16(af[mt], bfr[nt], acc[mt][nt], 0, 0, 0);
        __syncthreads();
    }

    #pragma unroll
    for (int nt = 0; nt < 2; ++nt) {
        int n = bx * 64 + wn + nt * 16 + l15;
        float bvv = bias[n];
        #pragma unroll
        for (int mt = 0; mt < 4; ++mt) {
            #pragma unroll
            for (int r = 0; r < 4; ++r) {
                int m = by * 128 + wm + mt * 16 + quad * 4 + r;
                out[(size_t)m * D_MODEL + n] = acc[mt][nt][r] + bvv;
            }
        }
    }
}

// ---------------------------------------------------------------------------
// Flash attention. Grid (32,32). XCD swizzle: blocks sharing a head's K/V
// (same bh) have identical (x & 7) => same XCD => that head's K/V (512 KB)
// stays L2-resident; each XCD serves 4 heads (2 MB of 4 MB L2).
// ---------------------------------------------------------------------------
__global__ __launch_bounds__(256, 3) void flash_attn(
    const u16* __restrict__ Q, const u16* __restrict__ K,
    const u16* __restrict__ Vt, const u64* __restrict__ maskbits,
    u16* __restrict__ O)
{
    __shared__ __align__(16) u16 ldsK[2][64 * 64];
    __shared__ __align__(16) u16 ldsV[2][64 * 64];
    __shared__ __align__(16) u16 ldsP[4][16 * 72];

    const int tid  = threadIdx.x;
    const int wv_  = tid >> 6;
    const int lane = tid & 63;
    const int quad = lane >> 4;
    const int l15  = lane & 15;
    // XCD-aware swizzle
    const int bh = ((blockIdx.x & 7) << 2) | (blockIdx.y & 3);     // 0..31
    const int qt = ((blockIdx.y >> 2) << 2) | (blockIdx.x >> 3);   // 0..31
    const int b  = bh >> 4, h = bh & 15;
    const int q0 = qt * 64 + wv_ * 16;

    const u16* Qb = Q  + (size_t)bh * SEQ * DEPTH;
    const u16* Kb = K  + (size_t)bh * SEQ * DEPTH;
    const u16* Vb = Vt + (size_t)bh * DEPTH * SEQ;
    const u64* MB = maskbits + (size_t)b * SEQ * (SEQ / 64);

    const int srow = tid >> 3;
    const int sc8  = tid & 7;
    const int swz  = ((sc8 ^ (srow & 7)) * 8);
    const int kdst0 = srow * 64 + swz;
    const int kdst1 = (srow + 32) * 64 + swz;

    const int xk0 = ((quad ^ (l15 & 7)) * 8);
    const int xk1 = (((4 + quad) ^ (l15 & 7)) * 8);

    bf16x8 aq0 = ldb8(&Qb[(q0 + l15) * DEPTH + quad * 8]);
    bf16x8 aq1 = ldb8(&Qb[(q0 + l15) * DEPTH + 32 + quad * 8]);

    f32x4 oa[4];
    for (int i = 0; i < 4; ++i) oa[i] = (f32x4){0.f, 0.f, 0.f, 0.f};
    float lrow[4] = {0.f, 0.f, 0.f, 0.f};

    u16* myP = ldsP[wv_];

    uint4 kreg0 = *(const uint4*)&Kb[(size_t)srow * DEPTH + sc8 * 8];
    uint4 kreg1 = *(const uint4*)&Kb[(size_t)(srow + 32) * DEPTH + sc8 * 8];
    uint4 vreg0 = *(const uint4*)&Vb[(size_t)srow * SEQ + sc8 * 8];
    uint4 vreg1 = *(const uint4*)&Vb[(size_t)(srow + 32) * SEQ + sc8 * 8];

    for (int it = 0; it < 32; ++it) {
        const int buf = it & 1;
        u16* Kl = ldsK[buf];
        u16* Vl = ldsV[buf];

        *(uint4*)&Kl[kdst0] = kreg0;
        *(uint4*)&Kl[kdst1] = kreg1;
        *(uint4*)&Vl[kdst0] = vreg0;
        *(uint4*)&Vl[kdst1] = vreg1;
        __syncthreads();

        if (it < 31) {
            const int kb2 = (it + 1) * 64;
            kreg0 = *(const uint4*)&Kb[(size_t)(kb2 + srow) * DEPTH + sc8 * 8];
            kreg1 = *(const uint4*)&Kb[(size_t)(kb2 + srow + 32) * DEPTH + sc8 * 8];
            vreg0 = *(const uint4*)&Vb[(size_t)srow * SEQ + kb2 + sc8 * 8];
            vreg1 = *(const uint4*)&Vb[(size_t)(srow + 32) * SEQ + kb2 + sc8 * 8];
        }

        u32 tlo[4], thi[4];
        #pragma unroll
        for (int r = 0; r < 4; ++r) {
            u64 t = MB[(size_t)(q0 + quad * 4 + r) * (SEQ / 64) + it] >> l15;
            tlo[r] = (u32)t;
            thi[r] = (u32)(t >> 32);
        }

        #pragma unroll
        for (int cc = 0; cc < 4; ++cc) {
            const int row = cc * 16 + l15;
            bf16x8 bk0 = ldb8(&Kl[row * 64 + xk0]);
            bf16x8 bk1 = ldb8(&Kl[row * 64 + xk1]);
            f32x4 z = (f32x4){0.f, 0.f, 0.f, 0.f};
            z = __builtin_amdgcn_mfma_f32_16x16x32_bf16(aq0, bk0, z, 0, 0, 0);
            z = __builtin_amdgcn_mfma_f32_16x16x32_bf16(aq1, bk1, z, 0, 0, 0);
            #pragma unroll
            for (int r = 0; r < 4; ++r) {
                u32 w   = (cc < 2) ? tlo[r] : thi[r];
                u32 bit = (cc & 1) ? ((w >> 16) & 1u) : (w & 1u);
                float e = __expf(z[r]);          // Q pre-scaled by 0.125
                float p = bit ? 0.f : e;
                lrow[r] += p;
                myP[(quad * 4 + r) * 72 + cc * 16 + l15] = f2b(p);
            }
        }

        __builtin_amdgcn_wave_barrier();
        __builtin_amdgcn_s_waitcnt(0xc07f);   // lgkmcnt(0)
        __builtin_amdgcn_wave_barrier();
        bf16x8 pa0 = ldb8(&myP[l15 * 72 + quad * 8]);
        bf16x8 pa1 = ldb8(&myP[l15 * 72 + 32 + quad * 8]);

        #pragma unroll
        for (int n = 0; n < 4; ++n) {
            const int row = n * 16 + l15;
            bf16x8 bv0 = ldb8(&Vl[row * 64 + xk0]);
            bf16x8 bv1 = ldb8(&Vl[row * 64 + xk1]);
            oa[n] = __builtin_amdgcn_mfma_f32_16x16x32_bf16(pa0, bv0, oa[n], 0, 0, 0);
            oa[n] = __builtin_amdgcn_mfma_f32_16x16x32_bf16(pa1, bv1, oa[n], 0, 0, 0);
        }
    }

    #pragma unroll
    for (int r = 0; r < 4; ++r) {
        float s = lrow[r];
        #pragma unroll
        for (int off = 1; off < 16; off <<= 1)
            s += __shfl_xor(s, off, 64);
        lrow[r] = 1.0f / s;
    }
    #pragma unroll
    for (int n = 0; n < 4; ++n)
        #pragma unroll
        for (int r = 0; r < 4; ++r) {
            int m = q0 + quad * 4 + r;
            O[((size_t)b * SEQ + m) * D_MODEL + h * DEPTH + n * 16 + l15] =
                f2b(oa[n][r] * lrow[r]);
        }
}

// ---------------------------------------------------------------------------
extern "C" void kernel_launch(void* const* d_in, const int* in_sizes, int n_in,
                              void* d_out, int out_size, void* d_ws, size_t ws_size,
                              hipStream_t stream) {
    const float* q    = (const float*)d_in[0];
    const float* k    = (const float*)d_in[1];
    const float* v    = (const float*)d_in[2];
    const float* mask = (const float*)d_in[3];
    const float* wq   = (const float*)d_in[4];
    const float* bq   = (const float*)d_in[5];
    const float* wk   = (const float*)d_in[6];
    const float* bk   = (const float*)d_in[7];
    const float* wv   = (const float*)d_in[8];
    const float* bv   = (const float*)d_in[9];
    const float* wo   = (const float*)d_in[10];
    const float* bo   = (const float*)d_in[11];

    // ws: [qws 8MB][kws 8MB][vtws 8MB][ows 8MB][maskbits 1MB]
    u16* base = (u16*)d_ws;
    const size_t seg = (size_t)BATCH * NHEADS * SEQ * DEPTH;  // 4M elems
    u16* qws  = base;
    u16* kws  = base + seg;
    u16* vtws = base + 2 * seg;
    u16* ows  = base + 3 * seg;
    u64* mbits = (u64*)(base + 4 * seg);

    dim3 blk(256);
    hipLaunchKernelGGL(pack_mask, dim3(BATCH * SEQ * (SEQ / 64) / 4), blk, 0, stream, mask, mbits);

    dim3 gp(D_MODEL / 128, MROWS / 128, 3);   // (8, 32, 3)
    hipLaunchKernelGGL(proj3, gp, blk, 0, stream,
                       q, k, v, wq, wk, wv, bq, bk, bv, qws, kws, vtws);

    dim3 ga(SEQ / 64, BATCH * NHEADS);        // (32, 32)
    hipLaunchKernelGGL(flash_attn, ga, blk, 0, stream, qws, kws, vtws, mbits, ows);

    dim3 go(D_MODEL / 64, MROWS / 128);       // (16, 32)
    hipLaunchKernelGGL(gemm_out, go, blk, 0, stream, ows, wo, bo, (float*)d_out);
}